// Round 3
// baseline (76.664 us; speedup 1.0000x reference)
//
#include <hip/hip_runtime.h>
#include <hip/hip_bf16.h>

#define NDIGIT 10
#define DIM_IN 256
#define DIM_OUT 784
#define BATCH 16384
#define BM 128                          // rows per block (4 waves x 32)
#define MAX_MT (BATCH / BM + NDIGIT)    // 138 worst-case M-tiles
#define NCB 7                           // 7 column blocks of 112
#define GEMM_BLOCKS (MAX_MT * NCB)      // 966

// ws layout (ints):
//  [0..10]   bucket offsets[11]
//  [12..22]  tile offsets[11] (BM=128 tiles)
//  [24]      total_tiles
//  [64 + j*16 + g]  per-hist-block partial counts (j<32, g<10)
//  [1024..17407]    idx[16384]
//  byte 69632..     W in bf16 (10*784*256 shorts)
#define WS_IDX 1024
#define WS_WBF_BYTES 69632

typedef __attribute__((ext_vector_type(4))) float f32x4;
typedef __attribute__((ext_vector_type(8))) short bf16x8;

__device__ __forceinline__ short f2bf(float f) {
    union { float f; unsigned u; } c; c.f = f;
    unsigned u = c.u;
    u += 0x7fffu + ((u >> 16) & 1u);   // RNE
    return (short)(u >> 16);
}

// blocks [0,980): convert megaW f32 -> bf16 into ws
// blocks [980,1012): per-512-row label histograms
__global__ void prep_k(const float* __restrict__ megaW,
                       const int* __restrict__ label,
                       int* __restrict__ wsi,
                       short* __restrict__ wbf) {
    int b = blockIdx.x, t = threadIdx.x;
    if (b < 980) {
        int base = b * 2048 + t * 8;       // 980*2048 = 2,007,040 exact
        f32x4 v0 = *(const f32x4*)(megaW + base);
        f32x4 v1 = *(const f32x4*)(megaW + base + 4);
        bf16x8 o;
        o[0] = f2bf(v0[0]); o[1] = f2bf(v0[1]); o[2] = f2bf(v0[2]); o[3] = f2bf(v0[3]);
        o[4] = f2bf(v1[0]); o[5] = f2bf(v1[1]); o[6] = f2bf(v1[2]); o[7] = f2bf(v1[3]);
        *(bf16x8*)(wbf + base) = o;
    } else {
        __shared__ int h[NDIGIT];
        int j = b - 980;
        if (t < NDIGIT) h[t] = 0;
        __syncthreads();
        int i0 = j * 512;
        atomicAdd(&h[label[i0 + t]], 1);
        atomicAdd(&h[label[i0 + 256 + t]], 1);
        __syncthreads();
        if (t < NDIGIT) wsi[64 + j * 16 + t] = h[t];
    }
}

// 32 blocks x 512 threads; block j owns rows [j*512, j*512+512)
__global__ void scatter2_k(const int* __restrict__ label, int* __restrict__ wsi) {
    __shared__ int tot[NDIGIT], bef[NDIGIT], base[NDIGIT + 1], cur[NDIGIT];
    int j = blockIdx.x, t = threadIdx.x;
    if (t < NDIGIT) {
        int s = 0, sb = 0;
        for (int jj = 0; jj < 32; ++jj) {
            int v = wsi[64 + jj * 16 + t];
            s += v;
            if (jj < j) sb += v;
        }
        tot[t] = s; bef[t] = sb;
    }
    __syncthreads();
    if (t == 0) {
        int off = 0;
        for (int g = 0; g < NDIGIT; ++g) { base[g] = off; off += tot[g]; }
        base[NDIGIT] = off;
    }
    __syncthreads();
    if (t < NDIGIT) cur[t] = base[t] + bef[t];
    __syncthreads();
    int i = j * 512 + t;
    int g = label[i];
    int r = atomicAdd(&cur[g], 1);
    wsi[WS_IDX + r] = i;
    if (j == 0 && t == 0) {
        int off = 0, toff = 0;
        for (int g2 = 0; g2 < NDIGIT; ++g2) {
            wsi[g2] = off; wsi[12 + g2] = toff;
            off += tot[g2]; toff += (tot[g2] + BM - 1) / BM;
        }
        wsi[10] = off; wsi[22] = toff; wsi[24] = toff;
    }
}

// Register-streaming GEMM: no LDS, no barriers. Each wave holds 32 theta
// rows stationary as A-frags; streams 7x16-col W subtiles from L2 into
// B-frags; fused bias+sigmoid epilogue with scattered stores.
__launch_bounds__(256, 4)   // target <=128 VGPR -> 16 waves/CU
__global__ void moe_gemm3_k(const float* __restrict__ theta,
                            const float* __restrict__ megab,
                            const int* __restrict__ wsi,
                            const short* __restrict__ wbf,
                            float* __restrict__ out) {
    // bijective XCD-chunked swizzle: each XCD gets a contiguous w-range ->
    // ~1-2 experts' W (<1 MB) + their theta rows resident in its L2.
    int Bid = blockIdx.x;
    const int q = GEMM_BLOCKS / 8, r = GEMM_BLOCKS % 8;   // 120, 6
    int xcd = Bid & 7, slot = Bid >> 3;
    int w = (xcd < r ? xcd * (q + 1) : r * (q + 1) + (xcd - r) * q) + slot;
    int mt = w / NCB, cb = w % NCB;

    int total = wsi[24];
    if (mt >= total) return;

    int g = 0;
    while (mt >= wsi[12 + g + 1]) ++g;
    int lt    = mt - wsi[12 + g];
    int start = wsi[g];
    int cnt   = wsi[g + 1] - start;

    int tid = threadIdx.x;
    int wv = tid >> 6, l = tid & 63, r16 = l & 15, kg = l >> 4;
    int wrow0 = lt * BM + wv * 32;          // expert-local first row of wave

    const int* idxg = wsi + WS_IDX + start;

    // A sources (clamped; stores are masked below)
    int ra0 = wrow0 + r16;      if (ra0 >= cnt) ra0 = cnt - 1;
    int ra1 = wrow0 + 16 + r16; if (ra1 >= cnt) ra1 = cnt - 1;
    const float* A0 = theta + (size_t)idxg[ra0] * DIM_IN;
    const float* A1 = theta + (size_t)idxg[ra1] * DIM_IN;

    bf16x8 a0[8], a1[8];
#pragma unroll
    for (int ks = 0; ks < 8; ++ks) {
        int k0 = ks * 32 + kg * 8;
        f32x4 u0 = *(const f32x4*)(A0 + k0);
        f32x4 u1 = *(const f32x4*)(A0 + k0 + 4);
        f32x4 v0 = *(const f32x4*)(A1 + k0);
        f32x4 v1 = *(const f32x4*)(A1 + k0 + 4);
        bf16x8 x, y;
        x[0] = f2bf(u0[0]); x[1] = f2bf(u0[1]); x[2] = f2bf(u0[2]); x[3] = f2bf(u0[3]);
        x[4] = f2bf(u1[0]); x[5] = f2bf(u1[1]); x[6] = f2bf(u1[2]); x[7] = f2bf(u1[3]);
        y[0] = f2bf(v0[0]); y[1] = f2bf(v0[1]); y[2] = f2bf(v0[2]); y[3] = f2bf(v0[3]);
        y[4] = f2bf(v1[0]); y[5] = f2bf(v1[1]); y[6] = f2bf(v1[2]); y[7] = f2bf(v1[3]);
        a0[ks] = x; a1[ks] = y;
    }

    // output rows (C/D layout: col=lane&15, row=kg*4+j within 16-row tile)
    int orow0[4], orow1[4];
#pragma unroll
    for (int j = 0; j < 4; ++j) {
        int rl0 = wrow0 + kg * 4 + j;
        int rl1 = rl0 + 16;
        orow0[j] = (rl0 < cnt) ? idxg[rl0] : -1;
        orow1[j] = (rl1 < cnt) ? idxg[rl1] : -1;
    }

    int colg = cb * 112 + r16;
    const short* Wg = wbf + (size_t)g * DIM_OUT * DIM_IN + (size_t)kg * 8;
    const float* bg = megab + (size_t)g * DIM_OUT;

#pragma unroll
    for (int ns = 0; ns < 7; ++ns) {
        const short* rp = Wg + (size_t)(colg + ns * 16) * DIM_IN;
        bf16x8 bb[8];
#pragma unroll
        for (int ks = 0; ks < 8; ++ks)
            bb[ks] = *(const bf16x8*)(rp + ks * 32);

        f32x4 acc0 = {0.f, 0.f, 0.f, 0.f}, acc1 = {0.f, 0.f, 0.f, 0.f};
#pragma unroll
        for (int ks = 0; ks < 8; ++ks) {
            acc0 = __builtin_amdgcn_mfma_f32_16x16x32_bf16(a0[ks], bb[ks], acc0, 0, 0, 0);
            acc1 = __builtin_amdgcn_mfma_f32_16x16x32_bf16(a1[ks], bb[ks], acc1, 0, 0, 0);
        }

        int oc = colg + ns * 16;
        float bias = bg[oc];
#pragma unroll
        for (int j = 0; j < 4; ++j) {
            if (orow0[j] >= 0) {
                float xv = acc0[j] + bias;
                __builtin_nontemporal_store(1.0f / (1.0f + __expf(-xv)),
                                            out + (size_t)orow0[j] * DIM_OUT + oc);
            }
            if (orow1[j] >= 0) {
                float xv = acc1[j] + bias;
                __builtin_nontemporal_store(1.0f / (1.0f + __expf(-xv)),
                                            out + (size_t)orow1[j] * DIM_OUT + oc);
            }
        }
    }
}

extern "C" void kernel_launch(void* const* d_in, const int* in_sizes, int n_in,
                              void* d_out, int out_size, void* d_ws, size_t ws_size,
                              hipStream_t stream) {
    const float* theta = (const float*)d_in[0];
    const int*   label = (const int*)d_in[1];
    const float* megaW = (const float*)d_in[2];
    const float* megab = (const float*)d_in[3];
    float* out = (float*)d_out;
    int* wsi = (int*)d_ws;
    short* wbf = (short*)((char*)d_ws + WS_WBF_BYTES);

    prep_k    <<<1012, 256, 0, stream>>>(megaW, label, wsi, wbf);
    scatter2_k<<<32, 512, 0, stream>>>(label, wsi);
    moe_gemm3_k<<<GEMM_BLOCKS, 256, 0, stream>>>(theta, megab, wsi, wbf, out);
}

// Round 4
// 47.826 us; speedup vs baseline: 1.6030x; 1.6030x over previous
//
#include <hip/hip_runtime.h>
#include <hip/hip_bf16.h>

#define NDIGIT 10
#define DIM_IN 256
#define DIM_OUT 784
#define BATCH 16384
#define BM 64                           // rows per block (4 waves x 16)
#define BN 112                          // cols per block (7 x 16)
#define NCB 7                           // 784 / 112
#define MAX_MT (BATCH / BM + NDIGIT)    // 266 worst-case M-tiles
#define GEMM_BLOCKS (MAX_MT * NCB)      // 1862

// ws layout (ints):
//  [0..10]   bucket offsets[11]
//  [12..22]  tile offsets[11] (BM=64 tiles)
//  [24]      total_tiles
//  [64 + j*16 + g]  per-hist-block partial counts (j<32, g<10)
//  [1024..17407]    idx[16384]
//  byte 69632..     W in bf16 (10*784*256 shorts)
#define WS_IDX 1024
#define WS_WBF_BYTES 69632

typedef __attribute__((ext_vector_type(4))) float f32x4;
typedef __attribute__((ext_vector_type(8))) short bf16x8;

__device__ __forceinline__ short f2bf(float f) {
    union { float f; unsigned u; } c; c.f = f;
    unsigned u = c.u;
    u += 0x7fffu + ((u >> 16) & 1u);   // RNE
    return (short)(u >> 16);
}

__device__ __forceinline__ void gload16(const void* gp, void* lp) {
    __builtin_amdgcn_global_load_lds(
        (const __attribute__((address_space(1))) void*)gp,
        (__attribute__((address_space(3))) void*)lp, 16, 0, 0);
}

// blocks [0,980): convert megaW f32 -> bf16 into ws
// blocks [980,1012): per-512-row label histograms
__global__ void prep_k(const float* __restrict__ megaW,
                       const int* __restrict__ label,
                       int* __restrict__ wsi,
                       short* __restrict__ wbf) {
    int b = blockIdx.x, t = threadIdx.x;
    if (b < 980) {
        int base = b * 2048 + t * 8;       // 980*2048 = 2,007,040 exact
        f32x4 v0 = *(const f32x4*)(megaW + base);
        f32x4 v1 = *(const f32x4*)(megaW + base + 4);
        bf16x8 o;
        o[0] = f2bf(v0[0]); o[1] = f2bf(v0[1]); o[2] = f2bf(v0[2]); o[3] = f2bf(v0[3]);
        o[4] = f2bf(v1[0]); o[5] = f2bf(v1[1]); o[6] = f2bf(v1[2]); o[7] = f2bf(v1[3]);
        *(bf16x8*)(wbf + base) = o;
    } else {
        __shared__ int h[NDIGIT];
        int j = b - 980;
        if (t < NDIGIT) h[t] = 0;
        __syncthreads();
        int i0 = j * 512;
        atomicAdd(&h[label[i0 + t]], 1);
        atomicAdd(&h[label[i0 + 256 + t]], 1);
        __syncthreads();
        if (t < NDIGIT) wsi[64 + j * 16 + t] = h[t];
    }
}

// 32 blocks x 512 threads; block j owns rows [j*512, j*512+512)
__global__ void scatter2_k(const int* __restrict__ label, int* __restrict__ wsi) {
    __shared__ int tot[NDIGIT], bef[NDIGIT], base[NDIGIT + 1], cur[NDIGIT];
    int j = blockIdx.x, t = threadIdx.x;
    if (t < NDIGIT) {
        int s = 0, sb = 0;
        for (int jj = 0; jj < 32; ++jj) {
            int v = wsi[64 + jj * 16 + t];
            s += v;
            if (jj < j) sb += v;
        }
        tot[t] = s; bef[t] = sb;
    }
    __syncthreads();
    if (t == 0) {
        int off = 0;
        for (int g = 0; g < NDIGIT; ++g) { base[g] = off; off += tot[g]; }
        base[NDIGIT] = off;
    }
    __syncthreads();
    if (t < NDIGIT) cur[t] = base[t] + bef[t];
    __syncthreads();
    int i = j * 512 + t;
    int g = label[i];
    int r = atomicAdd(&cur[g], 1);
    wsi[WS_IDX + r] = i;
    if (j == 0 && t == 0) {
        int off = 0, toff = 0;
        for (int g2 = 0; g2 < NDIGIT; ++g2) {
            wsi[g2] = off; wsi[12 + g2] = toff;
            off += tot[g2]; toff += (tot[g2] + BM - 1) / BM;
        }
        wsi[10] = off; wsi[22] = toff; wsi[24] = toff;
    }
}

// GEMM: 64x112 tile, K split into 2 halves of 128 -> LDS 28.7 KB -> 5 blocks/CU.
// W staged via global_load_lds (source pre-swizzled for conflict-free ds_read),
// A gathered to registers, plain cached stores.
__launch_bounds__(256, 4)
__global__ void moe_gemm4_k(const float* __restrict__ theta,
                            const float* __restrict__ megab,
                            const int* __restrict__ wsi,
                            const short* __restrict__ wbf,
                            float* __restrict__ out) {
    __shared__ short Bs[BN * 128];      // 28672 B: one K-half, XOR-swizzled

    // bijective XCD-chunked swizzle: an mt's 7 cb-blocks + same-expert
    // neighbors land on one XCD's L2 (theta + W reuse).
    int Bid = blockIdx.x;
    const int q = GEMM_BLOCKS / 8, r = GEMM_BLOCKS % 8;   // 232, 6
    int xcd = Bid & 7, slot = Bid >> 3;
    int w = (xcd < r ? xcd * (q + 1) : r * (q + 1) + (xcd - r) * q) + slot;
    int mt = w / NCB, cb = w % NCB;

    int total = wsi[24];
    if (mt >= total) return;            // uniform exit before barriers

    int g = 0;
    while (mt >= wsi[12 + g + 1]) ++g;
    int lt    = mt - wsi[12 + g];
    int start = wsi[g];
    int cnt   = wsi[g + 1] - start;
    int row0  = lt * BM;
    int rc    = min(BM, cnt - row0);    // valid rows in tile

    int tid = threadIdx.x;
    int wv = tid >> 6, l = tid & 63, r16 = l & 15, kg = l >> 4;

    // byte pointer to this block's W col-panel (112 rows x 512 B)
    const char* Wcb = (const char*)(wbf + ((size_t)g * DIM_OUT + (size_t)cb * BN) * DIM_IN);

    // ---- stage K-half 0 (async; overlaps the A-gather below) ----
#pragma unroll
    for (int it = 0; it < 7; ++it) {
        int lbyte = (it * 256 + tid) << 4;
        int L = lbyte ^ (((lbyte >> 8) & 7) << 4);       // inverse swizzle
        int srcoff = ((L >> 8) << 9) + (L & 255);        // row*512 + koff
        gload16(Wcb + srcoff, (char*)Bs + lbyte);
    }

    // ---- A fragments (gathered theta rows), full K ----
    const int* idxlist = wsi + WS_IDX + start + row0;
    int mloc = wv * 16 + r16;
    int asrc = (mloc < rc) ? idxlist[mloc] : idxlist[0];
    const float* Arow = theta + (size_t)asrc * DIM_IN;
    bf16x8 a[8];
#pragma unroll
    for (int ks = 0; ks < 8; ++ks) {
        int k0 = ks * 32 + kg * 8;
        f32x4 v0 = *(const f32x4*)(Arow + k0);
        f32x4 v1 = *(const f32x4*)(Arow + k0 + 4);
        bf16x8 af;
        af[0] = f2bf(v0[0]); af[1] = f2bf(v0[1]);
        af[2] = f2bf(v0[2]); af[3] = f2bf(v0[3]);
        af[4] = f2bf(v1[0]); af[5] = f2bf(v1[1]);
        af[6] = f2bf(v1[2]); af[7] = f2bf(v1[3]);
        a[ks] = af;
    }

    f32x4 acc[NCB];
#pragma unroll
    for (int ns = 0; ns < NCB; ++ns) acc[ns] = (f32x4){0.f, 0.f, 0.f, 0.f};

    // ---- K-half 0 compute ----
    __syncthreads();                    // half-0 staged (drains vmcnt)
#pragma unroll
    for (int ks = 0; ks < 4; ++ks)
#pragma unroll
        for (int ns = 0; ns < NCB; ++ns) {
            int n = ns * 16 + r16;
            int byte = (n << 8) + (ks << 6) + (kg << 4);
            byte ^= (n & 7) << 4;
            bf16x8 b = *(const bf16x8*)((const char*)Bs + byte);
            acc[ns] = __builtin_amdgcn_mfma_f32_16x16x32_bf16(a[ks], b, acc[ns], 0, 0, 0);
        }
    __syncthreads();                    // all waves done reading half 0

    // ---- stage K-half 1 ----
#pragma unroll
    for (int it = 0; it < 7; ++it) {
        int lbyte = (it * 256 + tid) << 4;
        int L = lbyte ^ (((lbyte >> 8) & 7) << 4);
        int srcoff = ((L >> 8) << 9) + (L & 255) + 256;  // +256 B = k 128..255
        gload16(Wcb + srcoff, (char*)Bs + lbyte);
    }
    __syncthreads();                    // half-1 staged

    // ---- K-half 1 compute ----
#pragma unroll
    for (int ks = 0; ks < 4; ++ks)
#pragma unroll
        for (int ns = 0; ns < NCB; ++ns) {
            int n = ns * 16 + r16;
            int byte = (n << 8) + (ks << 6) + (kg << 4);
            byte ^= (n & 7) << 4;
            bf16x8 b = *(const bf16x8*)((const char*)Bs + byte);
            acc[ns] = __builtin_amdgcn_mfma_f32_16x16x32_bf16(a[4 + ks], b, acc[ns], 0, 0, 0);
        }

    // ---- epilogue: bias + sigmoid + cached scattered stores ----
    const float* bg = megab + (size_t)g * DIM_OUT + (size_t)cb * BN;
    int rbase = wv * 16 + kg * 4;
    int orow[4];
#pragma unroll
    for (int j = 0; j < 4; ++j)
        orow[j] = (rbase + j < rc) ? idxlist[rbase + j] : -1;

#pragma unroll
    for (int ns = 0; ns < NCB; ++ns) {
        int nloc = ns * 16 + r16;
        float bias = bg[nloc];
#pragma unroll
        for (int j = 0; j < 4; ++j) {
            if (orow[j] >= 0) {
                float x = acc[ns][j] + bias;
                out[(size_t)orow[j] * DIM_OUT + cb * BN + nloc] = 1.0f / (1.0f + __expf(-x));
            }
        }
    }
}

extern "C" void kernel_launch(void* const* d_in, const int* in_sizes, int n_in,
                              void* d_out, int out_size, void* d_ws, size_t ws_size,
                              hipStream_t stream) {
    const float* theta = (const float*)d_in[0];
    const int*   label = (const int*)d_in[1];
    const float* megaW = (const float*)d_in[2];
    const float* megab = (const float*)d_in[3];
    float* out = (float*)d_out;
    int* wsi = (int*)d_ws;
    short* wbf = (short*)((char*)d_ws + WS_WBF_BYTES);

    prep_k    <<<1012, 256, 0, stream>>>(megaW, label, wsi, wbf);
    scatter2_k<<<32, 512, 0, stream>>>(label, wsi);
    moe_gemm4_k<<<GEMM_BLOCKS, 256, 0, stream>>>(theta, megab, wsi, wbf, out);
}

// Round 5
// 47.188 us; speedup vs baseline: 1.6246x; 1.0135x over previous
//
#include <hip/hip_runtime.h>
#include <hip/hip_bf16.h>

#define NDIGIT 10
#define DIM_IN 256
#define DIM_OUT 784
#define BATCH 16384
#define BM 64                           // rows per block (4 waves x 16)
#define BN 112                          // cols per block (7 x 16)
#define NCB 7                           // 784 / 112
#define MAX_MT (BATCH / BM + NDIGIT)    // 266 worst-case M-tiles
#define GEMM_BLOCKS (MAX_MT * NCB)      // 1862
#define QBYTES 14336                    // one K-quarter in LDS: 112 x 64 x 2B

// ws layout:
//  ints [0..10]   bucket offsets[11]
//  ints [12..22]  tile offsets[11]
//  ints [24]      total_tiles
//  ints [64 + j*16 + g]  per-hist-block partial counts (j<32, g<10)
//  ints [1024..17407]    idx[16384]
//  byte 69632..           W bf16 (2,007,040 shorts)
//  byte 4,083,712..       thsort bf16 (16384 x 256 shorts, sorted by label)
#define WS_IDX 1024
#define WS_WBF_BYTES 69632
#define WS_TH_BYTES (WS_WBF_BYTES + 2007040 * 2)          // 4,083,712
#define WS_NEED_OLD (WS_TH_BYTES)
#define WS_NEED_NEW (WS_TH_BYTES + BATCH * DIM_IN * 2)    // 12,472,320

typedef __attribute__((ext_vector_type(4))) float f32x4;
typedef __attribute__((ext_vector_type(8))) short bf16x8;

__device__ __forceinline__ short f2bf(float f) {
    union { float f; unsigned u; } c; c.f = f;
    unsigned u = c.u;
    u += 0x7fffu + ((u >> 16) & 1u);   // RNE
    return (short)(u >> 16);
}

__device__ __forceinline__ void gload16(const void* gp, void* lp) {
    __builtin_amdgcn_global_load_lds(
        (const __attribute__((address_space(1))) void*)gp,
        (__attribute__((address_space(3))) void*)lp, 16, 0, 0);
}

// blocks [0,980): convert megaW f32 -> bf16; blocks [980,1012): label histograms
__global__ void prep_k(const float* __restrict__ megaW,
                       const int* __restrict__ label,
                       int* __restrict__ wsi,
                       short* __restrict__ wbf) {
    int b = blockIdx.x, t = threadIdx.x;
    if (b < 980) {
        int base = b * 2048 + t * 8;
        f32x4 v0 = *(const f32x4*)(megaW + base);
        f32x4 v1 = *(const f32x4*)(megaW + base + 4);
        bf16x8 o;
        o[0] = f2bf(v0[0]); o[1] = f2bf(v0[1]); o[2] = f2bf(v0[2]); o[3] = f2bf(v0[3]);
        o[4] = f2bf(v1[0]); o[5] = f2bf(v1[1]); o[6] = f2bf(v1[2]); o[7] = f2bf(v1[3]);
        *(bf16x8*)(wbf + base) = o;
    } else {
        __shared__ int h[NDIGIT];
        int j = b - 980;
        if (t < NDIGIT) h[t] = 0;
        __syncthreads();
        int i0 = j * 512;
        atomicAdd(&h[label[i0 + t]], 1);
        atomicAdd(&h[label[i0 + 256 + t]], 1);
        __syncthreads();
        if (t < NDIGIT) wsi[64 + j * 16 + t] = h[t];
    }
}

// 32 blocks x 512 threads; block j owns rows [j*512, j*512+512)
__global__ void scatter2_k(const int* __restrict__ label, int* __restrict__ wsi) {
    __shared__ int tot[NDIGIT], bef[NDIGIT], base[NDIGIT + 1], cur[NDIGIT];
    int j = blockIdx.x, t = threadIdx.x;
    if (t < NDIGIT) {
        int s = 0, sb = 0;
        for (int jj = 0; jj < 32; ++jj) {
            int v = wsi[64 + jj * 16 + t];
            s += v;
            if (jj < j) sb += v;
        }
        tot[t] = s; bef[t] = sb;
    }
    __syncthreads();
    if (t == 0) {
        int off = 0;
        for (int g = 0; g < NDIGIT; ++g) { base[g] = off; off += tot[g]; }
        base[NDIGIT] = off;
    }
    __syncthreads();
    if (t < NDIGIT) cur[t] = base[t] + bef[t];
    __syncthreads();
    int i = j * 512 + t;
    int g = label[i];
    int r = atomicAdd(&cur[g], 1);
    wsi[WS_IDX + r] = i;
    if (j == 0 && t == 0) {
        int off = 0, toff = 0;
        for (int g2 = 0; g2 < NDIGIT; ++g2) {
            wsi[g2] = off; wsi[12 + g2] = toff;
            off += tot[g2]; toff += (tot[g2] + BM - 1) / BM;
        }
        wsi[10] = off; wsi[22] = toff; wsi[24] = toff;
    }
}

// gather theta rows into sorted order, converted to bf16 (2048 blocks x 256)
__global__ void gth_k(const float* __restrict__ theta,
                      const int* __restrict__ wsi,
                      short* __restrict__ thsort) {
    int gid = blockIdx.x * 256 + threadIdx.x;   // 524288 threads
    int r = gid >> 5;                           // sorted row 0..16383
    int c8 = (gid & 31) << 3;                   // col 0,8,..,248
    int src = wsi[WS_IDX + r];
    const float* p = theta + (size_t)src * DIM_IN + c8;
    f32x4 v0 = *(const f32x4*)p;
    f32x4 v1 = *(const f32x4*)(p + 4);
    bf16x8 o;
    o[0] = f2bf(v0[0]); o[1] = f2bf(v0[1]); o[2] = f2bf(v0[2]); o[3] = f2bf(v0[3]);
    o[4] = f2bf(v1[0]); o[5] = f2bf(v1[1]); o[6] = f2bf(v1[2]); o[7] = f2bf(v1[3]);
    *(bf16x8*)(thsort + (size_t)r * DIM_IN + c8) = o;
}

// stage K-quarter q of the 112-row W panel into linear LDS (source pre-swizzled).
// Exactly 4 gload16 per thread (uniform per wave -> exact vmcnt counting);
// threads 128..255 of the last sweep duplicate threads 0..127 (benign).
__device__ __forceinline__ void stage_q(const char* Wcb, int q, char* Bq, int tid) {
#pragma unroll
    for (int it = 0; it < 4; ++it) {
        int chunk = it * 256 + tid;            // 0..1023 (896 real chunks)
        if (chunk >= 896) chunk -= 128;
        int lbyte = chunk << 4;
        int L = lbyte ^ ((((lbyte >> 7) & 7)) << 4);   // inverse of read swizzle
        int row = L >> 7, koff = L & 127;
        gload16(Wcb + row * 512 + q * 128 + koff, Bq + lbyte);
    }
}

#define COMPUTE(Q, BUF) do { \
    _Pragma("unroll") \
    for (int ksl = 0; ksl < 2; ++ksl) { \
        _Pragma("unroll") \
        for (int ns = 0; ns < NCB; ++ns) { \
            int n = ns * 16 + r16; \
            int byte = (n << 7) + (ksl << 6) + (kg << 4); \
            byte ^= (n & 7) << 4; \
            bf16x8 bfr = *(const bf16x8*)((const char*)(BUF) + byte); \
            acc[ns] = __builtin_amdgcn_mfma_f32_16x16x32_bf16(a[(Q) * 2 + ksl], bfr, acc[ns], 0, 0, 0); \
        } \
    } \
} while (0)

// Pipelined GEMM: A from pre-sorted bf16 (no convert, no gather), W quarters
// double-buffered with counted vmcnt + raw barriers.
__launch_bounds__(256, 4)
__global__ void moe_gemm5_k(const short* __restrict__ thsort,
                            const float* __restrict__ megab,
                            const int* __restrict__ wsi,
                            const short* __restrict__ wbf,
                            float* __restrict__ out) {
    __shared__ char Bs0[QBYTES];
    __shared__ char Bs1[QBYTES];

    int Bid = blockIdx.x;
    const int q8 = GEMM_BLOCKS / 8, r8 = GEMM_BLOCKS % 8;   // 232, 6
    int xcd = Bid & 7, slot = Bid >> 3;
    int w = (xcd < r8 ? xcd * (q8 + 1) : r8 * (q8 + 1) + (xcd - r8) * q8) + slot;
    int mt = w / NCB, cb = w % NCB;

    int total = wsi[24];
    if (mt >= total) return;            // uniform exit before any barrier

    int g = 0;
    while (mt >= wsi[12 + g + 1]) ++g;
    int lt    = mt - wsi[12 + g];
    int start = wsi[g];
    int cnt   = wsi[g + 1] - start;
    int row0  = lt * BM;
    int rc    = min(BM, cnt - row0);

    int tid = threadIdx.x;
    int wv = tid >> 6, l = tid & 63, r16 = l & 15, kg = l >> 4;

    // ---- A fragments: contiguous pre-converted rows (issued first = oldest vmem)
    int arow = start + row0 + wv * 16 + r16;
    if (arow > BATCH - 1) arow = BATCH - 1;
    const short* Ar = thsort + (size_t)arow * DIM_IN + kg * 8;
    bf16x8 a[8];
#pragma unroll
    for (int ks = 0; ks < 8; ++ks)
        a[ks] = *(const bf16x8*)(Ar + ks * 32);

    const int* idxlist = wsi + WS_IDX + start + row0;
    int rbase = wv * 16 + kg * 4;
    int orow[4];
#pragma unroll
    for (int j = 0; j < 4; ++j)
        orow[j] = (rbase + j < rc) ? idxlist[rbase + j] : -1;

    const char* Wcb = (const char*)(wbf + ((size_t)g * DIM_OUT + (size_t)cb * BN) * DIM_IN);

    // ---- prologue: stage quarters 0 and 1
    stage_q(Wcb, 0, Bs0, tid);
    stage_q(Wcb, 1, Bs1, tid);

    f32x4 acc[NCB];
#pragma unroll
    for (int ns = 0; ns < NCB; ++ns) acc[ns] = (f32x4){0.f, 0.f, 0.f, 0.f};

    asm volatile("s_waitcnt vmcnt(4)" ::: "memory");   // q0 landed (q1 in flight)
    __builtin_amdgcn_s_barrier();
    __builtin_amdgcn_sched_barrier(0);

    COMPUTE(0, Bs0);
    asm volatile("s_waitcnt lgkmcnt(0)" ::: "memory");
    __builtin_amdgcn_s_barrier();                      // all waves done reading Bs0
    stage_q(Wcb, 2, Bs0, tid);
    asm volatile("s_waitcnt vmcnt(4)" ::: "memory");   // q1 landed (q2 in flight)
    __builtin_amdgcn_s_barrier();
    __builtin_amdgcn_sched_barrier(0);

    COMPUTE(1, Bs1);
    asm volatile("s_waitcnt lgkmcnt(0)" ::: "memory");
    __builtin_amdgcn_s_barrier();                      // all waves done reading Bs1
    stage_q(Wcb, 3, Bs1, tid);
    asm volatile("s_waitcnt vmcnt(4)" ::: "memory");   // q2 landed (q3 in flight)
    __builtin_amdgcn_s_barrier();
    __builtin_amdgcn_sched_barrier(0);

    COMPUTE(2, Bs0);
    asm volatile("s_waitcnt lgkmcnt(0) vmcnt(0)" ::: "memory");  // q3 landed
    __builtin_amdgcn_s_barrier();
    __builtin_amdgcn_sched_barrier(0);

    COMPUTE(3, Bs1);

    // ---- epilogue: bias + sigmoid + cached scattered stores
    const float* bg = megab + (size_t)g * DIM_OUT + (size_t)cb * BN;
#pragma unroll
    for (int ns = 0; ns < NCB; ++ns) {
        int nloc = ns * 16 + r16;
        float bias = bg[nloc];
#pragma unroll
        for (int j = 0; j < 4; ++j) {
            if (orow[j] >= 0) {
                float x = acc[ns][j] + bias;
                out[(size_t)orow[j] * DIM_OUT + cb * BN + nloc] = 1.0f / (1.0f + __expf(-x));
            }
        }
    }
}

// =============== fallback (round-4 path, known 48 us) ===============
__launch_bounds__(256, 4)
__global__ void moe_gemm4_k(const float* __restrict__ theta,
                            const float* __restrict__ megab,
                            const int* __restrict__ wsi,
                            const short* __restrict__ wbf,
                            float* __restrict__ out) {
    __shared__ short Bsf[BN * 128];
    int Bid = blockIdx.x;
    const int q8 = GEMM_BLOCKS / 8, r8 = GEMM_BLOCKS % 8;
    int xcd = Bid & 7, slot = Bid >> 3;
    int w = (xcd < r8 ? xcd * (q8 + 1) : r8 * (q8 + 1) + (xcd - r8) * q8) + slot;
    int mt = w / NCB, cb = w % NCB;
    int total = wsi[24];
    if (mt >= total) return;
    int g = 0;
    while (mt >= wsi[12 + g + 1]) ++g;
    int lt    = mt - wsi[12 + g];
    int start = wsi[g];
    int cnt   = wsi[g + 1] - start;
    int row0  = lt * BM;
    int rc    = min(BM, cnt - row0);
    int tid = threadIdx.x;
    int wv = tid >> 6, l = tid & 63, r16 = l & 15, kg = l >> 4;
    const char* Wcb = (const char*)(wbf + ((size_t)g * DIM_OUT + (size_t)cb * BN) * DIM_IN);
#pragma unroll
    for (int it = 0; it < 7; ++it) {
        int lbyte = (it * 256 + tid) << 4;
        int L = lbyte ^ (((lbyte >> 8) & 7) << 4);
        int srcoff = ((L >> 8) << 9) + (L & 255);
        gload16(Wcb + srcoff, (char*)Bsf + lbyte);
    }
    const int* idxlist = wsi + WS_IDX + start + row0;
    int mloc = wv * 16 + r16;
    int asrc = (mloc < rc) ? idxlist[mloc] : idxlist[0];
    const float* Arow = (const float*)0;
    Arow = theta + (size_t)asrc * DIM_IN;
    bf16x8 a[8];
#pragma unroll
    for (int ks = 0; ks < 8; ++ks) {
        int k0 = ks * 32 + kg * 8;
        f32x4 v0 = *(const f32x4*)(Arow + k0);
        f32x4 v1 = *(const f32x4*)(Arow + k0 + 4);
        bf16x8 af;
        af[0] = f2bf(v0[0]); af[1] = f2bf(v0[1]);
        af[2] = f2bf(v0[2]); af[3] = f2bf(v0[3]);
        af[4] = f2bf(v1[0]); af[5] = f2bf(v1[1]);
        af[6] = f2bf(v1[2]); af[7] = f2bf(v1[3]);
        a[ks] = af;
    }
    f32x4 acc[NCB];
#pragma unroll
    for (int ns = 0; ns < NCB; ++ns) acc[ns] = (f32x4){0.f, 0.f, 0.f, 0.f};
    __syncthreads();
#pragma unroll
    for (int ks = 0; ks < 4; ++ks)
#pragma unroll
        for (int ns = 0; ns < NCB; ++ns) {
            int n = ns * 16 + r16;
            int byte = (n << 8) + (ks << 6) + (kg << 4);
            byte ^= (n & 7) << 4;
            bf16x8 b = *(const bf16x8*)((const char*)Bsf + byte);
            acc[ns] = __builtin_amdgcn_mfma_f32_16x16x32_bf16(a[ks], b, acc[ns], 0, 0, 0);
        }
    __syncthreads();
#pragma unroll
    for (int it = 0; it < 7; ++it) {
        int lbyte = (it * 256 + tid) << 4;
        int L = lbyte ^ (((lbyte >> 8) & 7) << 4);
        int srcoff = ((L >> 8) << 9) + (L & 255) + 256;
        gload16(Wcb + srcoff, (char*)Bsf + lbyte);
    }
    __syncthreads();
#pragma unroll
    for (int ks = 0; ks < 4; ++ks)
#pragma unroll
        for (int ns = 0; ns < NCB; ++ns) {
            int n = ns * 16 + r16;
            int byte = (n << 8) + (ks << 6) + (kg << 4);
            byte ^= (n & 7) << 4;
            bf16x8 b = *(const bf16x8*)((const char*)Bsf + byte);
            acc[ns] = __builtin_amdgcn_mfma_f32_16x16x32_bf16(a[4 + ks], b, acc[ns], 0, 0, 0);
        }
    const float* bg = megab + (size_t)g * DIM_OUT + (size_t)cb * BN;
    int rbase = wv * 16 + kg * 4;
    int orow[4];
#pragma unroll
    for (int j = 0; j < 4; ++j)
        orow[j] = (rbase + j < rc) ? idxlist[rbase + j] : -1;
#pragma unroll
    for (int ns = 0; ns < NCB; ++ns) {
        int nloc = ns * 16 + r16;
        float bias = bg[nloc];
#pragma unroll
        for (int j = 0; j < 4; ++j) {
            if (orow[j] >= 0) {
                float x = acc[ns][j] + bias;
                out[(size_t)orow[j] * DIM_OUT + cb * BN + nloc] = 1.0f / (1.0f + __expf(-x));
            }
        }
    }
}

extern "C" void kernel_launch(void* const* d_in, const int* in_sizes, int n_in,
                              void* d_out, int out_size, void* d_ws, size_t ws_size,
                              hipStream_t stream) {
    const float* theta = (const float*)d_in[0];
    const int*   label = (const int*)d_in[1];
    const float* megaW = (const float*)d_in[2];
    const float* megab = (const float*)d_in[3];
    float* out = (float*)d_out;
    int* wsi = (int*)d_ws;
    short* wbf = (short*)((char*)d_ws + WS_WBF_BYTES);

    prep_k    <<<1012, 256, 0, stream>>>(megaW, label, wsi, wbf);
    scatter2_k<<<32, 512, 0, stream>>>(label, wsi);

    if (ws_size >= (size_t)WS_NEED_NEW) {
        short* thsort = (short*)((char*)d_ws + WS_TH_BYTES);
        gth_k     <<<2048, 256, 0, stream>>>(theta, wsi, thsort);
        moe_gemm5_k<<<GEMM_BLOCKS, 256, 0, stream>>>(thsort, megab, wsi, wbf, out);
    } else {
        moe_gemm4_k<<<GEMM_BLOCKS, 256, 0, stream>>>(theta, megab, wsi, wbf, out);
    }
}